// Round 7
// baseline (442.449 us; speedup 1.0000x reference)
//
#include <hip/hip_runtime.h>
#include <hip/hip_fp16.h>
#include <math.h>

// Shapes (fixed): B=4, C=512, H=W=64 -> HW=4096
constexpr int BATCH = 4;
constexpr int HWDIM = 4096;
constexpr long CNT   = 2097152;              // 4096*512 elems per batch (one q/k/v matrix)
constexpr long ACNT  = 16777216;             // 4096*4096 attn elems per batch
constexpr int GSIZE = 65536;
constexpr float GN_EPS = 1e-5f;

typedef __attribute__((ext_vector_type(8))) _Float16 f16x8;
typedef __attribute__((ext_vector_type(4))) float f32x4;

__device__ __forceinline__ unsigned pkf16(float a, float b) {
  __half ha = __float2half(a), hb = __float2half(b);   // RTN
  return (unsigned)__half_as_ushort(ha) | ((unsigned)__half_as_ushort(hb) << 16);
}
__device__ __forceinline__ float2 up2(unsigned u) {
  __half2 h = *(__half2*)&u;
  return __half22float2(h);
}
// async global->LDS, 16B per lane; LDS dest = wave-uniform base + lane*16
__device__ __forceinline__ void gl_lds16(const void* g, void* l) {
  __builtin_amdgcn_global_load_lds((const __attribute__((address_space(1))) unsigned*)g,
                                   (__attribute__((address_space(3))) unsigned*)l, 16, 0, 0);
}
template<int N> __device__ __forceinline__ void wait_vmcnt() {
  if constexpr (N == 0)      asm volatile("s_waitcnt vmcnt(0)" ::: "memory");
  else if constexpr (N == 3) asm volatile("s_waitcnt vmcnt(3)" ::: "memory");
  else if constexpr (N == 4) asm volatile("s_waitcnt vmcnt(4)" ::: "memory");
  else if constexpr (N == 6) asm volatile("s_waitcnt vmcnt(6)" ::: "memory");
  else if constexpr (N == 8) asm volatile("s_waitcnt vmcnt(8)" ::: "memory");
  else if constexpr (N == 12) asm volatile("s_waitcnt vmcnt(12)" ::: "memory");
}

// ---------------- GroupNorm ----------------
// 512 blocks (4 per group) -> atomic partial sums into sacc[256] (zeroed by memset).
__global__ void gn_stats_kernel(const float* __restrict__ x, float* __restrict__ sacc) {
  const int blk = blockIdx.x;
  const int grp = blk >> 2;
  const float4* p = (const float4*)(x + (long)grp * GSIZE + (long)(blk & 3) * (GSIZE / 4));
  float s = 0.f, q = 0.f;
  for (int i = threadIdx.x; i < GSIZE / 16; i += 256) {
    float4 v = p[i];
    s += (v.x + v.y) + (v.z + v.w);
    q += (v.x * v.x + v.y * v.y) + (v.z * v.z + v.w * v.w);
  }
  #pragma unroll
  for (int o = 32; o > 0; o >>= 1) { s += __shfl_xor(s, o, 64); q += __shfl_xor(q, o, 64); }
  __shared__ float ls[4], lq[4];
  if ((threadIdx.x & 63) == 0) { ls[threadIdx.x >> 6] = s; lq[threadIdx.x >> 6] = q; }
  __syncthreads();
  if (threadIdx.x == 0) {
    atomicAdd(&sacc[grp * 2],     (ls[0] + ls[1]) + (ls[2] + ls[3]));
    atomicAdd(&sacc[grp * 2 + 1], (lq[0] + lq[1]) + (lq[2] + lq[3]));
  }
}

__global__ void gn_norm_f16(const float* __restrict__ x, const float* __restrict__ sacc,
                            const float* __restrict__ gw, const float* __restrict__ gb,
                            unsigned short* __restrict__ h) {
  long i = ((long)blockIdx.x * 256 + threadIdx.x) * 4;
  int c   = (int)((i >> 12) & 511);
  int grp = (int)(i >> 16);
  float S = sacc[grp * 2], Q = sacc[grp * 2 + 1];
  float m = S * (1.f / GSIZE);
  float r = rsqrtf(Q * (1.f / GSIZE) - m * m + GN_EPS);
  float w = gw[c] * r;
  float bia = gb[c] - m * w;
  float4 v = *(const float4*)(x + i);
  *(uint2*)(h + i) = (uint2){ pkf16(v.x * w + bia, v.y * w + bia),
                              pkf16(v.z * w + bia, v.w * w + bia) };
}

// ---------------- weights -> fp16 ----------------
__global__ void wcvt(const float* __restrict__ w0, const float* __restrict__ w1,
                     const float* __restrict__ w2, const float* __restrict__ w3,
                     unsigned short* __restrict__ o) {
  const float* src = blockIdx.y == 0 ? w0 : blockIdx.y == 1 ? w1 : blockIdx.y == 2 ? w2 : w3;
  long e = ((long)blockIdx.x * 256 + threadIdx.x) * 4;
  float4 v = *(const float4*)(src + e);
  *(uint2*)(o + (long)blockIdx.y * 262144 + e) = (uint2){ pkf16(v.x, v.y), pkf16(v.z, v.w) };
}

// ---------------- shared GEMM core: phase-split + counted vmcnt + setprio, NBUF-deep ----
// BMxBN tile, BK=32, NWMxNWN waves, per-wave (AM*16)x64, acc[AM][4].
// NBUF LDS buffers (3 or 4); stage buffer (step+NBUF-1) during step; end-of-step wait is
// vmcnt((NBUF-2)*L) so each buffer's loads get (NBUF-2)+ full steps in flight (T4: never
// drain to 0 in the main loop). Per K-step 2 phases, each: ds_read -> stage-issue ->
// BAR -> lgkmcnt(0) -> setprio(1) 16-MFMA setprio(0) -> BAR.
// WAR: stage target buf (step-1 mod NBUF) was fully read by the end of step-1.
// RAW: wait((NBUF-2)L) at end of step s => loads issued at step s-(NBUF-2)-1 landed.
// NOTE (rule #20): all acc[][] indices compile-time (round-4 spill lesson).
template<int BM, int BN, int NWM, int NWN, int AM, int K, int NBUF>
__device__ __forceinline__ void gemm_core(const unsigned short* __restrict__ Ab, long sA,
                                          const unsigned short* __restrict__ Bb, long sB,
                                          unsigned short* LB, const int t, f32x4 (&acc)[AM][4]) {
  constexpr int NW   = NWM * NWN;
  constexpr int APW  = BM / 16 / NW;       // A fragment-tiles staged per wave
  constexpr int BPW  = BN / 16 / NW;
  constexpr int L    = APW + BPW;          // loads per thread per K-step
  constexpr int BUFS = (BM + BN) * 32;     // shorts per buffer
  const int lane = t & 63, w = t >> 6;
  const int wm = (NWM == 2) ? (w & 1) : (w >> 1);
  const int wn = (NWM == 2) ? (w >> 1) : (w & 1);

  auto stageA = [&](int buf, int k0) {
    unsigned short* S = LB + buf * BUFS;
    #pragma unroll
    for (int i = 0; i < APW; i++) {
      int fb = w * APW + i;
      gl_lds16(Ab + (long)(fb * 16 + (lane & 15)) * sA + k0 + (lane >> 4) * 8, &S[fb * 512]);
    }
  };
  auto stageB = [&](int buf, int k0) {
    unsigned short* S = LB + buf * BUFS + BM * 32;
    #pragma unroll
    for (int i = 0; i < BPW; i++) {
      int fb = w * BPW + i;
      gl_lds16(Bb + (long)(fb * 16 + (lane & 15)) * sB + k0 + (lane >> 4) * 8, &S[fb * 512]);
    }
  };

  #pragma unroll
  for (int p = 0; p < NBUF - 1; p++) { stageA(p, p * 32); stageB(p, p * 32); }
  wait_vmcnt<(NBUF - 2) * L>();                      // buf0's L landed (per wave)
  __builtin_amdgcn_s_barrier();                      // ... for all waves

  int cur = 0;
  #pragma unroll 1
  for (int k0 = 0; k0 < K; k0 += 32) {
    const unsigned short* As = LB + cur * BUFS;
    const unsigned short* Bs = As + BM * 32;
    int nxt = cur + (NBUF - 1); if (nxt >= NBUF) nxt -= NBUF;
    const bool st = (k0 + (NBUF - 1) * 32 < K);

    // ---- phase A ----
    f16x8 a0[AM / 2], b[4];
    #pragma unroll
    for (int i = 0; i < AM / 2; i++)
      a0[i] = *(const f16x8*)&As[((wm * AM + i) * 64 + lane) * 8];
    #pragma unroll
    for (int j = 0; j < 4; j++)
      b[j] = *(const f16x8*)&Bs[((wn * 4 + j) * 64 + lane) * 8];
    if (st) stageA(nxt, k0 + (NBUF - 1) * 32);
    __builtin_amdgcn_s_barrier();
    asm volatile("s_waitcnt lgkmcnt(0)" ::: "memory");
    __builtin_amdgcn_sched_barrier(0);
    __builtin_amdgcn_s_setprio(1);
    #pragma unroll
    for (int i = 0; i < AM / 2; i++)
      #pragma unroll
      for (int j = 0; j < 4; j++)
        acc[i][j] = __builtin_amdgcn_mfma_f32_16x16x32_f16(a0[i], b[j], acc[i][j], 0, 0, 0);
    __builtin_amdgcn_s_setprio(0);
    __builtin_amdgcn_s_barrier();

    // ---- phase B ----
    f16x8 a1[AM / 2];
    #pragma unroll
    for (int i = 0; i < AM / 2; i++)
      a1[i] = *(const f16x8*)&As[((wm * AM + AM / 2 + i) * 64 + lane) * 8];
    if (st) stageB(nxt, k0 + (NBUF - 1) * 32);
    __builtin_amdgcn_s_barrier();
    asm volatile("s_waitcnt lgkmcnt(0)" ::: "memory");
    __builtin_amdgcn_sched_barrier(0);
    __builtin_amdgcn_s_setprio(1);
    #pragma unroll
    for (int i = 0; i < AM / 2; i++)
      #pragma unroll
      for (int j = 0; j < 4; j++)
        acc[AM / 2 + i][j] =
            __builtin_amdgcn_mfma_f32_16x16x32_f16(a1[i], b[j], acc[AM / 2 + i][j], 0, 0, 0);
    __builtin_amdgcn_s_setprio(0);
    // counted drain: keep (NBUF-2) stage-groups in flight in steady state
    if (st)                               wait_vmcnt<(NBUF - 2) * L>();
    else if (NBUF == 4 && k0 + 64 < K)    wait_vmcnt<L>();
    else                                  wait_vmcnt<0>();
    __builtin_amdgcn_s_barrier();
    cur = cur + 1; if (cur >= NBUF) cur = 0;
  }
  __syncthreads();                                   // LB reusable by epilogue
}

// fp16 coalesced epilogue via LDS, 64-row chunks (aliases staging LDS).
// Fully unrolled: every acc index compile-time.
template<int BM, int BN, int NWM, int NWN, int AM>
__device__ __forceinline__ void store_f16(unsigned short* LB, f32x4 (&acc)[AM][4], const int t,
                                          unsigned short* __restrict__ outp, long sO,
                                          const float* __restrict__ bias) {
  const int lane = t & 63, w = t >> 6;
  const int wm = (NWM == 2) ? (w & 1) : (w >> 1);
  const int wn = (NWM == 2) ? (w >> 1) : (w & 1);
  const int lm = lane & 15, quad = lane >> 4;
  constexpr int NT  = NWM * NWN * 64;
  constexpr int TPR = BN / 8;                        // threads per output row
  constexpr int RPR = NT / TPR;                      // rows per round
  constexpr int CPW = AM / 4;                        // 64-row chunks per wave
  #pragma unroll
  for (int c = 0; c < BM / 64; c++) {
    __syncthreads();
    if (wm == c / CPW) {
      #pragma unroll
      for (int i2 = 0; i2 < 4; i2++)
        #pragma unroll
        for (int j = 0; j < 4; j++) {
          int rr = i2 * 16 + quad * 4;
          int cc = wn * 64 + j * 16 + lm;
          float bb = bias ? bias[cc] : 0.f;
          #pragma unroll
          for (int r = 0; r < 4; r++)
            LB[(rr + r) * (BN + 8) + cc] =
                __half_as_ushort(__float2half(acc[(c % CPW) * 4 + i2][j][r] + bb));
        }
    }
    __syncthreads();
    #pragma unroll
    for (int k = 0; k < 64 / RPR; k++) {
      int ro = k * RPR + t / TPR;
      int co = (t % TPR) * 8;
      uint4 v = *(const uint4*)&LB[ro * (BN + 8) + co];
      *(uint4*)&outp[(long)(c * 64 + ro) * sO + co] = v;
    }
  }
}

// ---------------- QKV projection: M=16384, N=512, K=512; 256x128, 4 waves, grid (64,4,3) ----
__launch_bounds__(256, 2)
__global__ void proj_qkv(const unsigned short* __restrict__ A, const unsigned short* __restrict__ WF,
                         const float* __restrict__ bq, const float* __restrict__ bk,
                         const float* __restrict__ bv, unsigned short* __restrict__ outq) {
  __shared__ __align__(16) unsigned short LB[36864];   // 72 KB: 3 x 24 KB buffers
  const int z = blockIdx.z;
  const unsigned short* W = WF + (long)z * 262144;
  const float* bias = z == 0 ? bq : z == 1 ? bk : bv;
  unsigned short* outp = outq + (long)z * 8388608;
  const int m0 = blockIdx.x * 256, n0 = blockIdx.y * 128;
  const int t = threadIdx.x;

  f32x4 acc[8][4];
  #pragma unroll
  for (int i = 0; i < 8; i++)
    #pragma unroll
    for (int j = 0; j < 4; j++) acc[i][j] = (f32x4){0.f, 0.f, 0.f, 0.f};

  gemm_core<256, 128, 2, 2, 8, 512, 3>(A + (long)m0 * 512, 512, W + (long)n0 * 512, 512, LB, t, acc);
  store_f16<256, 128, 2, 2, 8>(LB, acc, t, outp + (long)m0 * 512 + n0, 512, bias + n0);
}

// ---------------- Output projection: f32 out + residual; 256x128, 4 waves, grid (64,4) ----
__launch_bounds__(256, 2)
__global__ void proj_out(const unsigned short* __restrict__ A, const unsigned short* __restrict__ W,
                         const float* __restrict__ bias, const float* __restrict__ res,
                         float* __restrict__ outv) {
  __shared__ __align__(16) unsigned short LB[36864];
  const int m0 = blockIdx.x * 256, n0 = blockIdx.y * 128;
  const int t = threadIdx.x;

  f32x4 acc[8][4];
  #pragma unroll
  for (int i = 0; i < 8; i++)
    #pragma unroll
    for (int j = 0; j < 4; j++) acc[i][j] = (f32x4){0.f, 0.f, 0.f, 0.f};

  gemm_core<256, 128, 2, 2, 8, 512, 3>(A + (long)m0 * 512, 512, W + (long)n0 * 512, 512, LB, t, acc);

  const int lane = t & 63, w = t >> 6, wm = w & 1, wn = w >> 1;
  const int lm = lane & 15, quad = lane >> 4;
  #pragma unroll
  for (int i = 0; i < 8; i++)
    #pragma unroll
    for (int j = 0; j < 4; j++) {
      int nn = m0 + wm * 128 + i * 16 + quad * 4;
      int cc = n0 + wn * 64 + j * 16 + lm;
      float bb = bias[cc];
      #pragma unroll
      for (int r = 0; r < 4; r++) {
        long idx = (long)(nn + r) * 512 + cc;
        outv[idx] = acc[i][j][r] + bb + res[idx];
      }
    }
}

// ---------------- Transpose fp16 (batched): (512,4096)-view -> [4096][512] ----------------
__global__ void transpose_f16(const unsigned short* __restrict__ qb,
                              const unsigned short* __restrict__ kb,
                              unsigned short* __restrict__ tr) {
  __shared__ __align__(16) unsigned short ld[64 * 72];
  const int zb = blockIdx.z;
  const int b = zb >> 1;
  const unsigned short* in = (zb & 1 ? kb : qb) + (long)b * CNT;
  unsigned short* o = tr + (long)b * 2 * CNT + (zb & 1 ? CNT : 0);
  const int n0 = blockIdx.x * 64, c0 = blockIdx.y * 64;
  const int t = threadIdx.x;
  unsigned* ld32 = (unsigned*)ld;
  {
    const int p = t >> 3, cg = t & 7;
    uint4 r0 = *(const uint4*)(in + (long)(c0 + 2 * p) * 4096 + n0 + 8 * cg);
    uint4 r1 = *(const uint4*)(in + (long)(c0 + 2 * p + 1) * 4096 + n0 + 8 * cg);
    unsigned aw[4] = { r0.x, r0.y, r0.z, r0.w };
    unsigned bw[4] = { r1.x, r1.y, r1.z, r1.w };
    #pragma unroll
    for (int i = 0; i < 4; i++) {
      ld32[(8 * cg + 2 * i) * 36 + p]     = (aw[i] & 0xFFFFu) | (bw[i] << 16);
      ld32[(8 * cg + 2 * i + 1) * 36 + p] = (aw[i] >> 16) | (bw[i] & 0xFFFF0000u);
    }
  }
  __syncthreads();
  {
    const int n = t >> 2, cg2 = t & 3;
    uint4 o0 = *(const uint4*)(ld + n * 72 + 16 * cg2);
    uint4 o1 = *(const uint4*)(ld + n * 72 + 16 * cg2 + 8);
    *(uint4*)(o + (long)(n0 + n) * 512 + c0 + 16 * cg2)     = o0;
    *(uint4*)(o + (long)(n0 + n) * 512 + c0 + 16 * cg2 + 8) = o1;
  }
}

// ---------------- QK^T: 256x256 tiles, 8 waves, 4-deep pipeline, grid (16,16,4) ----------------
__launch_bounds__(512, 1)
__global__ void qk_f16(const unsigned short* __restrict__ tr, unsigned short* __restrict__ attn) {
  __shared__ __align__(16) unsigned short LB[65536];   // 128 KB: 4 x 32 KB buffers
  const int b = blockIdx.z;
  const unsigned short* qT = tr + (long)b * 2 * CNT;
  const unsigned short* kT = qT + CNT;
  const int n0 = blockIdx.x * 256, m0 = blockIdx.y * 256;
  const int t = threadIdx.x;

  f32x4 acc[8][4];
  #pragma unroll
  for (int i = 0; i < 8; i++)
    #pragma unroll
    for (int j = 0; j < 4; j++) acc[i][j] = (f32x4){0.f, 0.f, 0.f, 0.f};

  gemm_core<256, 256, 2, 4, 8, 512, 4>(qT + (long)n0 * 512, 512, kT + (long)m0 * 512, 512, LB, t, acc);
  store_f16<256, 256, 2, 4, 8>(LB, acc, t, attn + (long)b * ACNT + (long)n0 * 4096 + m0, 4096,
                               nullptr);
}

// ---------------- Row softmax: fp16 in, fp16 out, in place (all batches) ----------------
__global__ void softmax_f16ip(unsigned short* __restrict__ attn) {
  unsigned short* p = attn + (long)blockIdx.x * HWDIM;
  const int t = threadIdx.x;                 // 16 shorts per thread
  uint4 u0 = *(const uint4*)(p + t * 16);
  uint4 u1 = *(const uint4*)(p + t * 16 + 8);
  float v[16];
  {
    unsigned uu[8] = { u0.x, u0.y, u0.z, u0.w, u1.x, u1.y, u1.z, u1.w };
    #pragma unroll
    for (int i = 0; i < 8; i++) { float2 f = up2(uu[i]); v[2*i] = f.x; v[2*i+1] = f.y; }
  }
  float mx = -1e30f;
  #pragma unroll
  for (int i = 0; i < 16; i++) mx = fmaxf(mx, v[i]);
  #pragma unroll
  for (int o = 32; o > 0; o >>= 1) mx = fmaxf(mx, __shfl_xor(mx, o, 64));
  __shared__ float rmax[4], rsum[4];
  if ((t & 63) == 0) rmax[t >> 6] = mx;
  __syncthreads();
  mx = fmaxf(fmaxf(rmax[0], rmax[1]), fmaxf(rmax[2], rmax[3]));
  float s = 0.f;
  #pragma unroll
  for (int i = 0; i < 16; i++) { v[i] = __expf(v[i] - mx); s += v[i]; }
  #pragma unroll
  for (int o = 32; o > 0; o >>= 1) s += __shfl_xor(s, o, 64);
  if ((t & 63) == 0) rsum[t >> 6] = s;
  __syncthreads();
  s = (rsum[0] + rsum[1]) + (rsum[2] + rsum[3]);
  float inv = 1.f / s;
  uint4 w0, w1;
  w0.x = pkf16(v[0]*inv,  v[1]*inv);  w0.y = pkf16(v[2]*inv,  v[3]*inv);
  w0.z = pkf16(v[4]*inv,  v[5]*inv);  w0.w = pkf16(v[6]*inv,  v[7]*inv);
  w1.x = pkf16(v[8]*inv,  v[9]*inv);  w1.y = pkf16(v[10]*inv, v[11]*inv);
  w1.z = pkf16(v[12]*inv, v[13]*inv); w1.w = pkf16(v[14]*inv, v[15]*inv);
  *(uint4*)(p + t * 16)     = w0;
  *(uint4*)(p + t * 16 + 8) = w1;
}

// ---------------- PV: 256x128 tiles, 8 waves (4Mx2N), 4-deep, grid (16,4,4), K=4096 --------
__launch_bounds__(512, 1)
__global__ void pv_f16(const unsigned short* __restrict__ P, const unsigned short* __restrict__ V,
                       unsigned short* __restrict__ ot) {
  __shared__ __align__(16) unsigned short LB[49152];   // 96 KB: 4 x 24 KB
  const int b = blockIdx.z;
  const unsigned short* Pb = P + (long)b * ACNT;
  const unsigned short* Vb = V + (long)b * CNT;
  unsigned short* Ob = ot + (long)b * CNT;
  const int n0 = blockIdx.x * 256, c0 = blockIdx.y * 128;
  const int t = threadIdx.x;

  f32x4 acc[4][4];
  #pragma unroll
  for (int i = 0; i < 4; i++)
    #pragma unroll
    for (int j = 0; j < 4; j++) acc[i][j] = (f32x4){0.f, 0.f, 0.f, 0.f};

  gemm_core<256, 128, 4, 2, 4, 4096, 4>(Pb + (long)n0 * 4096, 4096, Vb + (long)c0 * 4096, 4096,
                                        LB, t, acc);
  store_f16<256, 128, 4, 2, 4>(LB, acc, t, Ob + (long)n0 * 512 + c0, 512, nullptr);
}

// ---------------- launch ----------------
extern "C" void kernel_launch(void* const* d_in, const int* in_sizes, int n_in,
                              void* d_out, int out_size, void* d_ws, size_t ws_size,
                              hipStream_t stream) {
  (void)in_sizes; (void)n_in; (void)out_size; (void)ws_size;
  const float* x  = (const float*)d_in[0];
  const float* gw = (const float*)d_in[1];
  const float* gb = (const float*)d_in[2];
  const float* wq = (const float*)d_in[3];
  const float* bq = (const float*)d_in[4];
  const float* wk = (const float*)d_in[5];
  const float* bk = (const float*)d_in[6];
  const float* wv = (const float*)d_in[7];
  const float* bv = (const float*)d_in[8];
  const float* wo = (const float*)d_in[9];
  const float* bo = (const float*)d_in[10];
  float* out = (float*)d_out;

  // Workspace (~226 MB of the 256 MiB, all fp16 except sacc):
  //  [attn 128MB | h 16MB aliases start][qf 16][kf 16][vf 16][tr 32][ot 16][wf 2][sacc]
  unsigned short* attn = (unsigned short*)d_ws;
  unsigned short* h    = attn;                 // dead before first qk write
  unsigned short* qf   = attn + 4 * ACNT;
  unsigned short* kf   = qf + 8388608;
  unsigned short* vf   = kf + 8388608;
  unsigned short* tr   = vf + 8388608;         // 4 batches x (qT|kT)
  unsigned short* ot   = tr + 16777216;
  unsigned short* wf   = ot + 8388608;
  float* sacc = (float*)(wf + 1048576);

  hipMemsetAsync(sacc, 0, 256 * sizeof(float), stream);
  gn_stats_kernel<<<dim3(512), dim3(256), 0, stream>>>(x, sacc);
  gn_norm_f16<<<dim3(8192), dim3(256), 0, stream>>>(x, sacc, gw, gb, h);
  wcvt<<<dim3(256, 4), dim3(256), 0, stream>>>(wq, wk, wv, wo, wf);

  proj_qkv<<<dim3(64, 4, 3), 256, 0, stream>>>(h, wf, bq, bk, bv, qf);

  transpose_f16<<<dim3(64, 8, 8), 256, 0, stream>>>(qf, kf, tr);
  qk_f16<<<dim3(16, 16, 4), 512, 0, stream>>>(tr, attn);
  softmax_f16ip<<<dim3(16384), 256, 0, stream>>>(attn);
  pv_f16<<<dim3(16, 4, 4), 512, 0, stream>>>(attn, vf, ot);

  proj_out<<<dim3(64, 4), 256, 0, stream>>>(ot, wf + 786432, bo, x, out);
}

// Round 8
// 434.720 us; speedup vs baseline: 1.0178x; 1.0178x over previous
//
#include <hip/hip_runtime.h>
#include <hip/hip_fp16.h>
#include <math.h>
#include <utility>

// Shapes (fixed): B=4, C=512, H=W=64 -> HW=4096
constexpr int BATCH = 4;
constexpr int HWDIM = 4096;
constexpr long CNT   = 2097152;              // 4096*512 elems per batch (one q/k/v matrix)
constexpr long ACNT  = 16777216;             // 4096*4096 attn elems per batch
constexpr int GSIZE = 65536;
constexpr float GN_EPS = 1e-5f;

typedef __attribute__((ext_vector_type(8))) _Float16 f16x8;
typedef __attribute__((ext_vector_type(4))) float f32x4;

template<int N> using ic = std::integral_constant<int, N>;
template<bool B> using bc = std::integral_constant<bool, B>;

template<int N, typename F, int... Is>
__device__ __forceinline__ void static_for_impl(F&& f, std::integer_sequence<int, Is...>) {
  (f(std::integral_constant<int, Is>{}), ...);
}
template<int N, typename F>
__device__ __forceinline__ void static_for(F&& f) {
  static_for_impl<N>(static_cast<F&&>(f), std::make_integer_sequence<int, N>{});
}

__device__ __forceinline__ unsigned pkf16(float a, float b) {
  __half ha = __float2half(a), hb = __float2half(b);   // RTN
  return (unsigned)__half_as_ushort(ha) | ((unsigned)__half_as_ushort(hb) << 16);
}
__device__ __forceinline__ float2 up2(unsigned u) {
  __half2 h = *(__half2*)&u;
  return __half22float2(h);
}
// async global->LDS, 16B per lane; LDS dest = wave-uniform base + lane*16
__device__ __forceinline__ void gl_lds16(const void* g, void* l) {
  __builtin_amdgcn_global_load_lds((const __attribute__((address_space(1))) unsigned*)g,
                                   (__attribute__((address_space(3))) unsigned*)l, 16, 0, 0);
}
template<int N> __device__ __forceinline__ void wait_vmcnt() {
  if constexpr (N == 0)      asm volatile("s_waitcnt vmcnt(0)" ::: "memory");
  else if constexpr (N == 3) asm volatile("s_waitcnt vmcnt(3)" ::: "memory");
  else if constexpr (N == 4) asm volatile("s_waitcnt vmcnt(4)" ::: "memory");
  else if constexpr (N == 6) asm volatile("s_waitcnt vmcnt(6)" ::: "memory");
  else if constexpr (N == 8) asm volatile("s_waitcnt vmcnt(8)" ::: "memory");
  else if constexpr (N == 12) asm volatile("s_waitcnt vmcnt(12)" ::: "memory");
}

// ---------------- GroupNorm ----------------
// 512 blocks (4 per group) -> atomic partial sums into sacc[256] (zeroed by memset).
__global__ void gn_stats_kernel(const float* __restrict__ x, float* __restrict__ sacc) {
  const int blk = blockIdx.x;
  const int grp = blk >> 2;
  const float4* p = (const float4*)(x + (long)grp * GSIZE + (long)(blk & 3) * (GSIZE / 4));
  float s = 0.f, q = 0.f;
  for (int i = threadIdx.x; i < GSIZE / 16; i += 256) {
    float4 v = p[i];
    s += (v.x + v.y) + (v.z + v.w);
    q += (v.x * v.x + v.y * v.y) + (v.z * v.z + v.w * v.w);
  }
  #pragma unroll
  for (int o = 32; o > 0; o >>= 1) { s += __shfl_xor(s, o, 64); q += __shfl_xor(q, o, 64); }
  __shared__ float ls[4], lq[4];
  if ((threadIdx.x & 63) == 0) { ls[threadIdx.x >> 6] = s; lq[threadIdx.x >> 6] = q; }
  __syncthreads();
  if (threadIdx.x == 0) {
    atomicAdd(&sacc[grp * 2],     (ls[0] + ls[1]) + (ls[2] + ls[3]));
    atomicAdd(&sacc[grp * 2 + 1], (lq[0] + lq[1]) + (lq[2] + lq[3]));
  }
}

__global__ void gn_norm_f16(const float* __restrict__ x, const float* __restrict__ sacc,
                            const float* __restrict__ gw, const float* __restrict__ gb,
                            unsigned short* __restrict__ h) {
  long i = ((long)blockIdx.x * 256 + threadIdx.x) * 4;
  int c   = (int)((i >> 12) & 511);
  int grp = (int)(i >> 16);
  float S = sacc[grp * 2], Q = sacc[grp * 2 + 1];
  float m = S * (1.f / GSIZE);
  float r = rsqrtf(Q * (1.f / GSIZE) - m * m + GN_EPS);
  float w = gw[c] * r;
  float bia = gb[c] - m * w;
  float4 v = *(const float4*)(x + i);
  *(uint2*)(h + i) = (uint2){ pkf16(v.x * w + bia, v.y * w + bia),
                              pkf16(v.z * w + bia, v.w * w + bia) };
}

// ---------------- weights -> fp16 ----------------
__global__ void wcvt(const float* __restrict__ w0, const float* __restrict__ w1,
                     const float* __restrict__ w2, const float* __restrict__ w3,
                     unsigned short* __restrict__ o) {
  const float* src = blockIdx.y == 0 ? w0 : blockIdx.y == 1 ? w1 : blockIdx.y == 2 ? w2 : w3;
  long e = ((long)blockIdx.x * 256 + threadIdx.x) * 4;
  float4 v = *(const float4*)(src + e);
  *(uint2*)(o + (long)blockIdx.y * 262144 + e) = (uint2){ pkf16(v.x, v.y), pkf16(v.z, v.w) };
}

// ---------------- shared GEMM core: r7 schedule with COMPILE-TIME indices ----------------
// Same phase/barrier/wait/setprio rhythm as round 7; the only change is that every
// buffer index, LDS offset and (for K<=512) k-offset is a constexpr, so addresses fold
// into offset immediates and hoist out of the loop (the measured VALUBusy=17.5% was
// per-iteration address recompute serializing each phase's LDS reads behind VALU).
// Wait ladder (verified ≡ r7): steady (NBUF-2)*L; tail L*(NBUF-2-u) clamped at 0.
// NOTE (rule #20): all acc[][] indices compile-time.
template<int BM, int BN, int NWM, int NWN, int AM, int K, int NBUF>
__device__ __forceinline__ void gemm_core(const unsigned short* __restrict__ Ab, long sA,
                                          const unsigned short* __restrict__ Bb, long sB,
                                          unsigned short* LB, const int t, f32x4 (&acc)[AM][4]) {
  constexpr int NW   = NWM * NWN;
  constexpr int APW  = BM / 16 / NW;       // A fragment-tiles staged per wave
  constexpr int BPW  = BN / 16 / NW;
  constexpr int L    = APW + BPW;          // loads per thread per K-step
  constexpr int BUFS = (BM + BN) * 32;     // shorts per buffer
  constexpr int S    = K / 32;             // total K-steps
  const int lane = t & 63, w = t >> 6;
  const int wm = (NWM == 2) ? (w & 1) : (w >> 1);
  const int wn = (NWM == 2) ? (w >> 1) : (w & 1);

  auto stageA = [&](int buf, int k0) {
    unsigned short* Sb = LB + buf * BUFS;
    #pragma unroll
    for (int i = 0; i < APW; i++) {
      int fb = w * APW + i;
      gl_lds16(Ab + (long)(fb * 16 + (lane & 15)) * sA + k0 + (lane >> 4) * 8, &Sb[fb * 512]);
    }
  };
  auto stageB = [&](int buf, int k0) {
    unsigned short* Sb = LB + buf * BUFS + BM * 32;
    #pragma unroll
    for (int i = 0; i < BPW; i++) {
      int fb = w * BPW + i;
      gl_lds16(Bb + (long)(fb * 16 + (lane & 15)) * sB + k0 + (lane >> 4) * 8, &Sb[fb * 512]);
    }
  };

  // one K-step (BK=32), buf/st/W all compile-time
  auto step = [&](auto BUFC, int k0, auto STC, auto WC) {
    constexpr int buf = decltype(BUFC)::value;
    constexpr bool st = decltype(STC)::value;
    constexpr int W   = decltype(WC)::value;
    constexpr int nxt = (buf + NBUF - 1) % NBUF;
    const unsigned short* As = LB + buf * BUFS;
    const unsigned short* Bs = As + BM * 32;

    // ---- phase A ----
    f16x8 a0[AM / 2], b[4];
    #pragma unroll
    for (int i = 0; i < AM / 2; i++)
      a0[i] = *(const f16x8*)&As[((wm * AM + i) * 64 + lane) * 8];
    #pragma unroll
    for (int j = 0; j < 4; j++)
      b[j] = *(const f16x8*)&Bs[((wn * 4 + j) * 64 + lane) * 8];
    if constexpr (st) stageA(nxt, k0 + (NBUF - 1) * 32);
    __builtin_amdgcn_s_barrier();
    asm volatile("s_waitcnt lgkmcnt(0)" ::: "memory");
    __builtin_amdgcn_sched_barrier(0);
    __builtin_amdgcn_s_setprio(1);
    #pragma unroll
    for (int i = 0; i < AM / 2; i++)
      #pragma unroll
      for (int j = 0; j < 4; j++)
        acc[i][j] = __builtin_amdgcn_mfma_f32_16x16x32_f16(a0[i], b[j], acc[i][j], 0, 0, 0);
    __builtin_amdgcn_s_setprio(0);
    __builtin_amdgcn_s_barrier();

    // ---- phase B ----
    f16x8 a1[AM / 2];
    #pragma unroll
    for (int i = 0; i < AM / 2; i++)
      a1[i] = *(const f16x8*)&As[((wm * AM + AM / 2 + i) * 64 + lane) * 8];
    if constexpr (st) stageB(nxt, k0 + (NBUF - 1) * 32);
    __builtin_amdgcn_s_barrier();
    asm volatile("s_waitcnt lgkmcnt(0)" ::: "memory");
    __builtin_amdgcn_sched_barrier(0);
    __builtin_amdgcn_s_setprio(1);
    #pragma unroll
    for (int i = 0; i < AM / 2; i++)
      #pragma unroll
      for (int j = 0; j < 4; j++)
        acc[AM / 2 + i][j] =
            __builtin_amdgcn_mfma_f32_16x16x32_f16(a1[i], b[j], acc[AM / 2 + i][j], 0, 0, 0);
    __builtin_amdgcn_s_setprio(0);
    wait_vmcnt<W>();
    __builtin_amdgcn_s_barrier();
  };

  // prologue: stage steps 0..NBUF-2 into bufs 0..NBUF-2
  static_for<NBUF - 1>([&](auto pc) {
    constexpr int p = decltype(pc)::value;
    stageA(p, p * 32); stageB(p, p * 32);
  });
  wait_vmcnt<(NBUF - 2) * L>();
  __builtin_amdgcn_s_barrier();

  if constexpr (S <= 16) {
    // fully static: k0, buf, st, W all constexpr
    static_for<S>([&](auto sc) {
      constexpr int s   = decltype(sc)::value;
      constexpr int lo  = (s < S - NBUF) ? s : (S - NBUF);
      constexpr int cnt = lo - (s - NBUF + 2);
      step(ic<s % NBUF>{}, s * 32, bc<(s + NBUF - 1 < S)>{}, ic<L * (cnt < 0 ? 0 : cnt)>{});
    });
  } else {
    // main: unroll NBUF steps per iteration (buf compile-time), steady waits
    #pragma unroll 1
    for (int kb = 0; kb + NBUF * 32 < K; kb += NBUF * 32)
      static_for<NBUF>([&](auto uc) {
        constexpr int u = decltype(uc)::value;
        step(ic<u>{}, kb + u * 32, bc<true>{}, ic<(NBUF - 2) * L>{});
      });
    // tail iteration: only u==0 stages (target = last step); wait ladder down to 0
    {
      const int kb = K - NBUF * 32;
      static_for<NBUF>([&](auto uc) {
        constexpr int u = decltype(uc)::value;
        constexpr int W = (NBUF - 2 - u) > 0 ? L * (NBUF - 2 - u) : 0;
        step(ic<u>{}, kb + u * 32, bc<(u == 0)>{}, ic<W>{});
      });
    }
  }
  __syncthreads();                                   // LB reusable by epilogue
}

// fp16 coalesced epilogue via LDS, 64-row chunks (aliases staging LDS).
// Fully unrolled: every acc index compile-time.
template<int BM, int BN, int NWM, int NWN, int AM>
__device__ __forceinline__ void store_f16(unsigned short* LB, f32x4 (&acc)[AM][4], const int t,
                                          unsigned short* __restrict__ outp, long sO,
                                          const float* __restrict__ bias) {
  const int lane = t & 63, w = t >> 6;
  const int wm = (NWM == 2) ? (w & 1) : (w >> 1);
  const int wn = (NWM == 2) ? (w >> 1) : (w & 1);
  const int lm = lane & 15, quad = lane >> 4;
  constexpr int NT  = NWM * NWN * 64;
  constexpr int TPR = BN / 8;                        // threads per output row
  constexpr int RPR = NT / TPR;                      // rows per round
  constexpr int CPW = AM / 4;                        // 64-row chunks per wave
  #pragma unroll
  for (int c = 0; c < BM / 64; c++) {
    __syncthreads();
    if (wm == c / CPW) {
      #pragma unroll
      for (int i2 = 0; i2 < 4; i2++)
        #pragma unroll
        for (int j = 0; j < 4; j++) {
          int rr = i2 * 16 + quad * 4;
          int cc = wn * 64 + j * 16 + lm;
          float bb = bias ? bias[cc] : 0.f;
          #pragma unroll
          for (int r = 0; r < 4; r++)
            LB[(rr + r) * (BN + 8) + cc] =
                __half_as_ushort(__float2half(acc[(c % CPW) * 4 + i2][j][r] + bb));
        }
    }
    __syncthreads();
    #pragma unroll
    for (int k = 0; k < 64 / RPR; k++) {
      int ro = k * RPR + t / TPR;
      int co = (t % TPR) * 8;
      uint4 v = *(const uint4*)&LB[ro * (BN + 8) + co];
      *(uint4*)&outp[(long)(c * 64 + ro) * sO + co] = v;
    }
  }
}

// ---------------- QKV projection: M=16384, N=512, K=512; 256x128, 4 waves, grid (64,4,3) ----
__launch_bounds__(256, 2)
__global__ void proj_qkv(const unsigned short* __restrict__ A, const unsigned short* __restrict__ WF,
                         const float* __restrict__ bq, const float* __restrict__ bk,
                         const float* __restrict__ bv, unsigned short* __restrict__ outq) {
  __shared__ __align__(16) unsigned short LB[36864];   // 72 KB: 3 x 24 KB buffers
  const int z = blockIdx.z;
  const unsigned short* W = WF + (long)z * 262144;
  const float* bias = z == 0 ? bq : z == 1 ? bk : bv;
  unsigned short* outp = outq + (long)z * 8388608;
  const int m0 = blockIdx.x * 256, n0 = blockIdx.y * 128;
  const int t = threadIdx.x;

  f32x4 acc[8][4];
  #pragma unroll
  for (int i = 0; i < 8; i++)
    #pragma unroll
    for (int j = 0; j < 4; j++) acc[i][j] = (f32x4){0.f, 0.f, 0.f, 0.f};

  gemm_core<256, 128, 2, 2, 8, 512, 3>(A + (long)m0 * 512, 512, W + (long)n0 * 512, 512, LB, t, acc);
  store_f16<256, 128, 2, 2, 8>(LB, acc, t, outp + (long)m0 * 512 + n0, 512, bias + n0);
}

// ---------------- Output projection: f32 out + residual; 256x128, 4 waves, grid (64,4) ----
__launch_bounds__(256, 2)
__global__ void proj_out(const unsigned short* __restrict__ A, const unsigned short* __restrict__ W,
                         const float* __restrict__ bias, const float* __restrict__ res,
                         float* __restrict__ outv) {
  __shared__ __align__(16) unsigned short LB[36864];
  const int m0 = blockIdx.x * 256, n0 = blockIdx.y * 128;
  const int t = threadIdx.x;

  f32x4 acc[8][4];
  #pragma unroll
  for (int i = 0; i < 8; i++)
    #pragma unroll
    for (int j = 0; j < 4; j++) acc[i][j] = (f32x4){0.f, 0.f, 0.f, 0.f};

  gemm_core<256, 128, 2, 2, 8, 512, 3>(A + (long)m0 * 512, 512, W + (long)n0 * 512, 512, LB, t, acc);

  const int lane = t & 63, w = t >> 6, wm = w & 1, wn = w >> 1;
  const int lm = lane & 15, quad = lane >> 4;
  #pragma unroll
  for (int i = 0; i < 8; i++)
    #pragma unroll
    for (int j = 0; j < 4; j++) {
      int nn = m0 + wm * 128 + i * 16 + quad * 4;
      int cc = n0 + wn * 64 + j * 16 + lm;
      float bb = bias[cc];
      #pragma unroll
      for (int r = 0; r < 4; r++) {
        long idx = (long)(nn + r) * 512 + cc;
        outv[idx] = acc[i][j][r] + bb + res[idx];
      }
    }
}

// ---------------- Transpose fp16 (batched): (512,4096)-view -> [4096][512] ----------------
__global__ void transpose_f16(const unsigned short* __restrict__ qb,
                              const unsigned short* __restrict__ kb,
                              unsigned short* __restrict__ tr) {
  __shared__ __align__(16) unsigned short ld[64 * 72];
  const int zb = blockIdx.z;
  const int b = zb >> 1;
  const unsigned short* in = (zb & 1 ? kb : qb) + (long)b * CNT;
  unsigned short* o = tr + (long)b * 2 * CNT + (zb & 1 ? CNT : 0);
  const int n0 = blockIdx.x * 64, c0 = blockIdx.y * 64;
  const int t = threadIdx.x;
  unsigned* ld32 = (unsigned*)ld;
  {
    const int p = t >> 3, cg = t & 7;
    uint4 r0 = *(const uint4*)(in + (long)(c0 + 2 * p) * 4096 + n0 + 8 * cg);
    uint4 r1 = *(const uint4*)(in + (long)(c0 + 2 * p + 1) * 4096 + n0 + 8 * cg);
    unsigned aw[4] = { r0.x, r0.y, r0.z, r0.w };
    unsigned bw[4] = { r1.x, r1.y, r1.z, r1.w };
    #pragma unroll
    for (int i = 0; i < 4; i++) {
      ld32[(8 * cg + 2 * i) * 36 + p]     = (aw[i] & 0xFFFFu) | (bw[i] << 16);
      ld32[(8 * cg + 2 * i + 1) * 36 + p] = (aw[i] >> 16) | (bw[i] & 0xFFFF0000u);
    }
  }
  __syncthreads();
  {
    const int n = t >> 2, cg2 = t & 3;
    uint4 o0 = *(const uint4*)(ld + n * 72 + 16 * cg2);
    uint4 o1 = *(const uint4*)(ld + n * 72 + 16 * cg2 + 8);
    *(uint4*)(o + (long)(n0 + n) * 512 + c0 + 16 * cg2)     = o0;
    *(uint4*)(o + (long)(n0 + n) * 512 + c0 + 16 * cg2 + 8) = o1;
  }
}

// ---------------- QK^T: 256x256 tiles, 8 waves, 4-deep static pipeline, grid (16,16,4) --------
__launch_bounds__(512, 1)
__global__ void qk_f16(const unsigned short* __restrict__ tr, unsigned short* __restrict__ attn) {
  __shared__ __align__(16) unsigned short LB[65536];   // 128 KB: 4 x 32 KB buffers
  const int b = blockIdx.z;
  const unsigned short* qT = tr + (long)b * 2 * CNT;
  const unsigned short* kT = qT + CNT;
  const int n0 = blockIdx.x * 256, m0 = blockIdx.y * 256;
  const int t = threadIdx.x;

  f32x4 acc[8][4];
  #pragma unroll
  for (int i = 0; i < 8; i++)
    #pragma unroll
    for (int j = 0; j < 4; j++) acc[i][j] = (f32x4){0.f, 0.f, 0.f, 0.f};

  gemm_core<256, 256, 2, 4, 8, 512, 4>(qT + (long)n0 * 512, 512, kT + (long)m0 * 512, 512, LB, t, acc);
  store_f16<256, 256, 2, 4, 8>(LB, acc, t, attn + (long)b * ACNT + (long)n0 * 4096 + m0, 4096,
                               nullptr);
}

// ---------------- Row softmax: fp16 in, fp16 out, in place (all batches) ----------------
__global__ void softmax_f16ip(unsigned short* __restrict__ attn) {
  unsigned short* p = attn + (long)blockIdx.x * HWDIM;
  const int t = threadIdx.x;                 // 16 shorts per thread
  uint4 u0 = *(const uint4*)(p + t * 16);
  uint4 u1 = *(const uint4*)(p + t * 16 + 8);
  float v[16];
  {
    unsigned uu[8] = { u0.x, u0.y, u0.z, u0.w, u1.x, u1.y, u1.z, u1.w };
    #pragma unroll
    for (int i = 0; i < 8; i++) { float2 f = up2(uu[i]); v[2*i] = f.x; v[2*i+1] = f.y; }
  }
  float mx = -1e30f;
  #pragma unroll
  for (int i = 0; i < 16; i++) mx = fmaxf(mx, v[i]);
  #pragma unroll
  for (int o = 32; o > 0; o >>= 1) mx = fmaxf(mx, __shfl_xor(mx, o, 64));
  __shared__ float rmax[4], rsum[4];
  if ((t & 63) == 0) rmax[t >> 6] = mx;
  __syncthreads();
  mx = fmaxf(fmaxf(rmax[0], rmax[1]), fmaxf(rmax[2], rmax[3]));
  float s = 0.f;
  #pragma unroll
  for (int i = 0; i < 16; i++) { v[i] = __expf(v[i] - mx); s += v[i]; }
  #pragma unroll
  for (int o = 32; o > 0; o >>= 1) s += __shfl_xor(s, o, 64);
  if ((t & 63) == 0) rsum[t >> 6] = s;
  __syncthreads();
  s = (rsum[0] + rsum[1]) + (rsum[2] + rsum[3]);
  float inv = 1.f / s;
  uint4 w0, w1;
  w0.x = pkf16(v[0]*inv,  v[1]*inv);  w0.y = pkf16(v[2]*inv,  v[3]*inv);
  w0.z = pkf16(v[4]*inv,  v[5]*inv);  w0.w = pkf16(v[6]*inv,  v[7]*inv);
  w1.x = pkf16(v[8]*inv,  v[9]*inv);  w1.y = pkf16(v[10]*inv, v[11]*inv);
  w1.z = pkf16(v[12]*inv, v[13]*inv); w1.w = pkf16(v[14]*inv, v[15]*inv);
  *(uint4*)(p + t * 16)     = w0;
  *(uint4*)(p + t * 16 + 8) = w1;
}

// ---------------- PV: 256x128 tiles, 8 waves (4Mx2N), unrolled 4-deep, grid (16,4,4) --------
__launch_bounds__(512, 1)
__global__ void pv_f16(const unsigned short* __restrict__ P, const unsigned short* __restrict__ V,
                       unsigned short* __restrict__ ot) {
  __shared__ __align__(16) unsigned short LB[49152];   // 96 KB: 4 x 24 KB
  const int b = blockIdx.z;
  const unsigned short* Pb = P + (long)b * ACNT;
  const unsigned short* Vb = V + (long)b * CNT;
  unsigned short* Ob = ot + (long)b * CNT;
  const int n0 = blockIdx.x * 256, c0 = blockIdx.y * 128;
  const int t = threadIdx.x;

  f32x4 acc[4][4];
  #pragma unroll
  for (int i = 0; i < 4; i++)
    #pragma unroll
    for (int j = 0; j < 4; j++) acc[i][j] = (f32x4){0.f, 0.f, 0.f, 0.f};

  gemm_core<256, 128, 4, 2, 4, 4096, 4>(Pb + (long)n0 * 4096, 4096, Vb + (long)c0 * 4096, 4096,
                                        LB, t, acc);
  store_f16<256, 128, 4, 2, 4>(LB, acc, t, Ob + (long)n0 * 512 + c0, 512, nullptr);
}

// ---------------- launch ----------------
extern "C" void kernel_launch(void* const* d_in, const int* in_sizes, int n_in,
                              void* d_out, int out_size, void* d_ws, size_t ws_size,
                              hipStream_t stream) {
  (void)in_sizes; (void)n_in; (void)out_size; (void)ws_size;
  const float* x  = (const float*)d_in[0];
  const float* gw = (const float*)d_in[1];
  const float* gb = (const float*)d_in[2];
  const float* wq = (const float*)d_in[3];
  const float* bq = (const float*)d_in[4];
  const float* wk = (const float*)d_in[5];
  const float* bk = (const float*)d_in[6];
  const float* wv = (const float*)d_in[7];
  const float* bv = (const float*)d_in[8];
  const float* wo = (const float*)d_in[9];
  const float* bo = (const float*)d_in[10];
  float* out = (float*)d_out;

  // Workspace (~226 MB of the 256 MiB, all fp16 except sacc):
  //  [attn 128MB | h 16MB aliases start][qf 16][kf 16][vf 16][tr 32][ot 16][wf 2][sacc]
  unsigned short* attn = (unsigned short*)d_ws;
  unsigned short* h    = attn;                 // dead before first qk write
  unsigned short* qf   = attn + 4 * ACNT;
  unsigned short* kf   = qf + 8388608;
  unsigned short* vf   = kf + 8388608;
  unsigned short* tr   = vf + 8388608;         // 4 batches x (qT|kT)
  unsigned short* ot   = tr + 16777216;
  unsigned short* wf   = ot + 8388608;
  float* sacc = (float*)(wf + 1048576);

  hipMemsetAsync(sacc, 0, 256 * sizeof(float), stream);
  gn_stats_kernel<<<dim3(512), dim3(256), 0, stream>>>(x, sacc);
  gn_norm_f16<<<dim3(8192), dim3(256), 0, stream>>>(x, sacc, gw, gb, h);
  wcvt<<<dim3(256, 4), dim3(256), 0, stream>>>(wq, wk, wv, wo, wf);

  proj_qkv<<<dim3(64, 4, 3), 256, 0, stream>>>(h, wf, bq, bk, bv, qf);

  transpose_f16<<<dim3(64, 8, 8), 256, 0, stream>>>(qf, kf, tr);
  qk_f16<<<dim3(16, 16, 4), 512, 0, stream>>>(tr, attn);
  softmax_f16ip<<<dim3(16384), 256, 0, stream>>>(attn);
  pv_f16<<<dim3(16, 4, 4), 512, 0, stream>>>(attn, vf, ot);

  proj_out<<<dim3(64, 4), 256, 0, stream>>>(ot, wf + 786432, bo, x, out);
}

// Round 9
// 433.423 us; speedup vs baseline: 1.0208x; 1.0030x over previous
//
#include <hip/hip_runtime.h>
#include <hip/hip_fp16.h>
#include <math.h>
#include <utility>

// Shapes (fixed): B=4, C=512, H=W=64 -> HW=4096
constexpr int BATCH = 4;
constexpr int HWDIM = 4096;
constexpr long CNT   = 2097152;              // 4096*512 elems per batch (one q/k/v matrix)
constexpr long ACNT  = 16777216;             // 4096*4096 attn elems per batch
constexpr int GSIZE = 65536;
constexpr float GN_EPS = 1e-5f;

typedef __attribute__((ext_vector_type(8))) _Float16 f16x8;
typedef __attribute__((ext_vector_type(4))) float f32x4;

template<int N> using ic = std::integral_constant<int, N>;
template<bool B> using bc = std::integral_constant<bool, B>;

template<int N, typename F, int... Is>
__device__ __forceinline__ void static_for_impl(F&& f, std::integer_sequence<int, Is...>) {
  (f(std::integral_constant<int, Is>{}), ...);
}
template<int N, typename F>
__device__ __forceinline__ void static_for(F&& f) {
  static_for_impl<N>(static_cast<F&&>(f), std::make_integer_sequence<int, N>{});
}

__device__ __forceinline__ unsigned pkf16(float a, float b) {
  __half ha = __float2half(a), hb = __float2half(b);   // RTN
  return (unsigned)__half_as_ushort(ha) | ((unsigned)__half_as_ushort(hb) << 16);
}
__device__ __forceinline__ float2 up2(unsigned u) {
  __half2 h = *(__half2*)&u;
  return __half22float2(h);
}
// async global->LDS, 16B per lane; LDS dest = wave-uniform base + lane*16
__device__ __forceinline__ void gl_lds16(const void* g, void* l) {
  __builtin_amdgcn_global_load_lds((const __attribute__((address_space(1))) unsigned*)g,
                                   (__attribute__((address_space(3))) unsigned*)l, 16, 0, 0);
}
template<int N> __device__ __forceinline__ void wait_vmcnt() {
  if constexpr (N == 0)      asm volatile("s_waitcnt vmcnt(0)" ::: "memory");
  else if constexpr (N == 3) asm volatile("s_waitcnt vmcnt(3)" ::: "memory");
  else if constexpr (N == 4) asm volatile("s_waitcnt vmcnt(4)" ::: "memory");
  else if constexpr (N == 6) asm volatile("s_waitcnt vmcnt(6)" ::: "memory");
  else if constexpr (N == 8) asm volatile("s_waitcnt vmcnt(8)" ::: "memory");
  else if constexpr (N == 12) asm volatile("s_waitcnt vmcnt(12)" ::: "memory");
}

// ---------------- GroupNorm ----------------
// 512 blocks (4 per group) -> atomic partial sums into sacc[256] (zeroed by memset).
__global__ void gn_stats_kernel(const float* __restrict__ x, float* __restrict__ sacc) {
  const int blk = blockIdx.x;
  const int grp = blk >> 2;
  const float4* p = (const float4*)(x + (long)grp * GSIZE + (long)(blk & 3) * (GSIZE / 4));
  float s = 0.f, q = 0.f;
  for (int i = threadIdx.x; i < GSIZE / 16; i += 256) {
    float4 v = p[i];
    s += (v.x + v.y) + (v.z + v.w);
    q += (v.x * v.x + v.y * v.y) + (v.z * v.z + v.w * v.w);
  }
  #pragma unroll
  for (int o = 32; o > 0; o >>= 1) { s += __shfl_xor(s, o, 64); q += __shfl_xor(q, o, 64); }
  __shared__ float ls[4], lq[4];
  if ((threadIdx.x & 63) == 0) { ls[threadIdx.x >> 6] = s; lq[threadIdx.x >> 6] = q; }
  __syncthreads();
  if (threadIdx.x == 0) {
    atomicAdd(&sacc[grp * 2],     (ls[0] + ls[1]) + (ls[2] + ls[3]));
    atomicAdd(&sacc[grp * 2 + 1], (lq[0] + lq[1]) + (lq[2] + lq[3]));
  }
}

__global__ void gn_norm_f16(const float* __restrict__ x, const float* __restrict__ sacc,
                            const float* __restrict__ gw, const float* __restrict__ gb,
                            unsigned short* __restrict__ h) {
  long i = ((long)blockIdx.x * 256 + threadIdx.x) * 4;
  int c   = (int)((i >> 12) & 511);
  int grp = (int)(i >> 16);
  float S = sacc[grp * 2], Q = sacc[grp * 2 + 1];
  float m = S * (1.f / GSIZE);
  float r = rsqrtf(Q * (1.f / GSIZE) - m * m + GN_EPS);
  float w = gw[c] * r;
  float bia = gb[c] - m * w;
  float4 v = *(const float4*)(x + i);
  *(uint2*)(h + i) = (uint2){ pkf16(v.x * w + bia, v.y * w + bia),
                              pkf16(v.z * w + bia, v.w * w + bia) };
}

// ---------------- weights -> fp16 ----------------
__global__ void wcvt(const float* __restrict__ w0, const float* __restrict__ w1,
                     const float* __restrict__ w2, const float* __restrict__ w3,
                     unsigned short* __restrict__ o) {
  const float* src = blockIdx.y == 0 ? w0 : blockIdx.y == 1 ? w1 : blockIdx.y == 2 ? w2 : w3;
  long e = ((long)blockIdx.x * 256 + threadIdx.x) * 4;
  float4 v = *(const float4*)(src + e);
  *(uint2*)(o + (long)blockIdx.y * 262144 + e) = (uint2){ pkf16(v.x, v.y), pkf16(v.z, v.w) };
}

// ---------------- shared GEMM core: compiler-scheduled phases, counted vmcnt, setprio ----
// Round-9 change (m141/m97 lesson): NO pre-MFMA barrier, NO asm lgkmcnt(0), NO
// sched_barrier(0). The compiler tracks its own ds_read->MFMA deps with fine-grained
// lgkmcnt(N), so early MFMAs overlap the tail of the LDS read drain (previous rounds
// forced drain-then-compute alternation -> measured 27% MfmaUtil ceiling).
// Kept: 1 s_barrier per phase (post-MFMA), counted vmcnt per K-step, setprio, static
// buffer indices, NBUF-deep staging.
// WAR: stage into buf b at step s; b was read at step s-1, and each wave reaches the
//   end-of-(s-1) barrier only after its MFMAs (which consumed those reads) issued.
// RAW: counted wait at end of step s-1 covers stage-loads of step s-3 (NBUF=4) / s-2
//   (NBUF=3) = the buffer step s reads; barrier publishes to all waves.
// NOTE (rule #20): all acc[][] indices compile-time.
template<int BM, int BN, int NWM, int NWN, int AM, int K, int NBUF>
__device__ __forceinline__ void gemm_core(const unsigned short* __restrict__ Ab, long sA,
                                          const unsigned short* __restrict__ Bb, long sB,
                                          unsigned short* LB, const int t, f32x4 (&acc)[AM][4]) {
  constexpr int NW   = NWM * NWN;
  constexpr int APW  = BM / 16 / NW;       // A fragment-tiles staged per wave
  constexpr int BPW  = BN / 16 / NW;
  constexpr int L    = APW + BPW;          // loads per thread per K-step
  constexpr int BUFS = (BM + BN) * 32;     // shorts per buffer
  constexpr int S    = K / 32;             // total K-steps
  const int lane = t & 63, w = t >> 6;
  const int wm = (NWM == 2) ? (w & 1) : (w >> 1);
  const int wn = (NWM == 2) ? (w >> 1) : (w & 1);

  auto stageA = [&](int buf, int k0) {
    unsigned short* Sb = LB + buf * BUFS;
    #pragma unroll
    for (int i = 0; i < APW; i++) {
      int fb = w * APW + i;
      gl_lds16(Ab + (long)(fb * 16 + (lane & 15)) * sA + k0 + (lane >> 4) * 8, &Sb[fb * 512]);
    }
  };
  auto stageB = [&](int buf, int k0) {
    unsigned short* Sb = LB + buf * BUFS + BM * 32;
    #pragma unroll
    for (int i = 0; i < BPW; i++) {
      int fb = w * BPW + i;
      gl_lds16(Bb + (long)(fb * 16 + (lane & 15)) * sB + k0 + (lane >> 4) * 8, &Sb[fb * 512]);
    }
  };

  // one K-step (BK=32), buf/st/W all compile-time
  auto step = [&](auto BUFC, int k0, auto STC, auto WC) {
    constexpr int buf = decltype(BUFC)::value;
    constexpr bool st = decltype(STC)::value;
    constexpr int W   = decltype(WC)::value;
    constexpr int nxt = (buf + NBUF - 1) % NBUF;
    const unsigned short* As = LB + buf * BUFS;
    const unsigned short* Bs = As + BM * 32;

    // ---- phase A: reads + stage issue + MFMA (compiler-interleaved) ----
    f16x8 a0[AM / 2], b[4];
    #pragma unroll
    for (int i = 0; i < AM / 2; i++)
      a0[i] = *(const f16x8*)&As[((wm * AM + i) * 64 + lane) * 8];
    #pragma unroll
    for (int j = 0; j < 4; j++)
      b[j] = *(const f16x8*)&Bs[((wn * 4 + j) * 64 + lane) * 8];
    if constexpr (st) stageA(nxt, k0 + (NBUF - 1) * 32);
    __builtin_amdgcn_s_setprio(1);
    #pragma unroll
    for (int i = 0; i < AM / 2; i++)
      #pragma unroll
      for (int j = 0; j < 4; j++)
        acc[i][j] = __builtin_amdgcn_mfma_f32_16x16x32_f16(a0[i], b[j], acc[i][j], 0, 0, 0);
    __builtin_amdgcn_s_setprio(0);
    __builtin_amdgcn_s_barrier();

    // ---- phase B ----
    f16x8 a1[AM / 2];
    #pragma unroll
    for (int i = 0; i < AM / 2; i++)
      a1[i] = *(const f16x8*)&As[((wm * AM + AM / 2 + i) * 64 + lane) * 8];
    if constexpr (st) stageB(nxt, k0 + (NBUF - 1) * 32);
    __builtin_amdgcn_s_setprio(1);
    #pragma unroll
    for (int i = 0; i < AM / 2; i++)
      #pragma unroll
      for (int j = 0; j < 4; j++)
        acc[AM / 2 + i][j] =
            __builtin_amdgcn_mfma_f32_16x16x32_f16(a1[i], b[j], acc[AM / 2 + i][j], 0, 0, 0);
    __builtin_amdgcn_s_setprio(0);
    wait_vmcnt<W>();
    __builtin_amdgcn_s_barrier();
  };

  // prologue: stage steps 0..NBUF-2 into bufs 0..NBUF-2
  static_for<NBUF - 1>([&](auto pc) {
    constexpr int p = decltype(pc)::value;
    stageA(p, p * 32); stageB(p, p * 32);
  });
  wait_vmcnt<(NBUF - 2) * L>();
  __builtin_amdgcn_s_barrier();

  if constexpr (S <= 16) {
    // fully static: k0, buf, st, W all constexpr
    static_for<S>([&](auto sc) {
      constexpr int s   = decltype(sc)::value;
      constexpr int lo  = (s < S - NBUF) ? s : (S - NBUF);
      constexpr int cnt = lo - (s - NBUF + 2);
      step(ic<s % NBUF>{}, s * 32, bc<(s + NBUF - 1 < S)>{}, ic<L * (cnt < 0 ? 0 : cnt)>{});
    });
  } else {
    // main: unroll NBUF steps per iteration (buf compile-time), steady waits
    #pragma unroll 1
    for (int kb = 0; kb + NBUF * 32 < K; kb += NBUF * 32)
      static_for<NBUF>([&](auto uc) {
        constexpr int u = decltype(uc)::value;
        step(ic<u>{}, kb + u * 32, bc<true>{}, ic<(NBUF - 2) * L>{});
      });
    // tail iteration: only u==0 stages (target = last step); wait ladder down to 0
    {
      const int kb = K - NBUF * 32;
      static_for<NBUF>([&](auto uc) {
        constexpr int u = decltype(uc)::value;
        constexpr int W = (NBUF - 2 - u) > 0 ? L * (NBUF - 2 - u) : 0;
        step(ic<u>{}, kb + u * 32, bc<(u == 0)>{}, ic<W>{});
      });
    }
  }
  __syncthreads();                                   // LB reusable by epilogue
}

// fp16 coalesced epilogue via LDS, 64-row chunks (aliases staging LDS).
// Fully unrolled: every acc index compile-time.
template<int BM, int BN, int NWM, int NWN, int AM>
__device__ __forceinline__ void store_f16(unsigned short* LB, f32x4 (&acc)[AM][4], const int t,
                                          unsigned short* __restrict__ outp, long sO,
                                          const float* __restrict__ bias) {
  const int lane = t & 63, w = t >> 6;
  const int wm = (NWM == 2) ? (w & 1) : (w >> 1);
  const int wn = (NWM == 2) ? (w >> 1) : (w & 1);
  const int lm = lane & 15, quad = lane >> 4;
  constexpr int NT  = NWM * NWN * 64;
  constexpr int TPR = BN / 8;                        // threads per output row
  constexpr int RPR = NT / TPR;                      // rows per round
  constexpr int CPW = AM / 4;                        // 64-row chunks per wave
  #pragma unroll
  for (int c = 0; c < BM / 64; c++) {
    __syncthreads();
    if (wm == c / CPW) {
      #pragma unroll
      for (int i2 = 0; i2 < 4; i2++)
        #pragma unroll
        for (int j = 0; j < 4; j++) {
          int rr = i2 * 16 + quad * 4;
          int cc = wn * 64 + j * 16 + lm;
          float bb = bias ? bias[cc] : 0.f;
          #pragma unroll
          for (int r = 0; r < 4; r++)
            LB[(rr + r) * (BN + 8) + cc] =
                __half_as_ushort(__float2half(acc[(c % CPW) * 4 + i2][j][r] + bb));
        }
    }
    __syncthreads();
    #pragma unroll
    for (int k = 0; k < 64 / RPR; k++) {
      int ro = k * RPR + t / TPR;
      int co = (t % TPR) * 8;
      uint4 v = *(const uint4*)&LB[ro * (BN + 8) + co];
      *(uint4*)&outp[(long)(c * 64 + ro) * sO + co] = v;
    }
  }
}

// ---------------- QKV projection: M=16384, N=512, K=512; 256x128, 4 waves, grid (64,4,3) ----
__launch_bounds__(256, 2)
__global__ void proj_qkv(const unsigned short* __restrict__ A, const unsigned short* __restrict__ WF,
                         const float* __restrict__ bq, const float* __restrict__ bk,
                         const float* __restrict__ bv, unsigned short* __restrict__ outq) {
  __shared__ __align__(16) unsigned short LB[36864];   // 72 KB: 3 x 24 KB buffers
  const int z = blockIdx.z;
  const unsigned short* W = WF + (long)z * 262144;
  const float* bias = z == 0 ? bq : z == 1 ? bk : bv;
  unsigned short* outp = outq + (long)z * 8388608;
  const int m0 = blockIdx.x * 256, n0 = blockIdx.y * 128;
  const int t = threadIdx.x;

  f32x4 acc[8][4];
  #pragma unroll
  for (int i = 0; i < 8; i++)
    #pragma unroll
    for (int j = 0; j < 4; j++) acc[i][j] = (f32x4){0.f, 0.f, 0.f, 0.f};

  gemm_core<256, 128, 2, 2, 8, 512, 3>(A + (long)m0 * 512, 512, W + (long)n0 * 512, 512, LB, t, acc);
  store_f16<256, 128, 2, 2, 8>(LB, acc, t, outp + (long)m0 * 512 + n0, 512, bias + n0);
}

// ---------------- Output projection: f32 out + residual; 256x128, 4 waves, grid (64,4) ----
__launch_bounds__(256, 2)
__global__ void proj_out(const unsigned short* __restrict__ A, const unsigned short* __restrict__ W,
                         const float* __restrict__ bias, const float* __restrict__ res,
                         float* __restrict__ outv) {
  __shared__ __align__(16) unsigned short LB[36864];
  const int m0 = blockIdx.x * 256, n0 = blockIdx.y * 128;
  const int t = threadIdx.x;

  f32x4 acc[8][4];
  #pragma unroll
  for (int i = 0; i < 8; i++)
    #pragma unroll
    for (int j = 0; j < 4; j++) acc[i][j] = (f32x4){0.f, 0.f, 0.f, 0.f};

  gemm_core<256, 128, 2, 2, 8, 512, 3>(A + (long)m0 * 512, 512, W + (long)n0 * 512, 512, LB, t, acc);

  const int lane = t & 63, w = t >> 6, wm = w & 1, wn = w >> 1;
  const int lm = lane & 15, quad = lane >> 4;
  #pragma unroll
  for (int i = 0; i < 8; i++)
    #pragma unroll
    for (int j = 0; j < 4; j++) {
      int nn = m0 + wm * 128 + i * 16 + quad * 4;
      int cc = n0 + wn * 64 + j * 16 + lm;
      float bb = bias[cc];
      #pragma unroll
      for (int r = 0; r < 4; r++) {
        long idx = (long)(nn + r) * 512 + cc;
        outv[idx] = acc[i][j][r] + bb + res[idx];
      }
    }
}

// ---------------- Transpose fp16 (batched): (512,4096)-view -> [4096][512] ----------------
__global__ void transpose_f16(const unsigned short* __restrict__ qb,
                              const unsigned short* __restrict__ kb,
                              unsigned short* __restrict__ tr) {
  __shared__ __align__(16) unsigned short ld[64 * 72];
  const int zb = blockIdx.z;
  const int b = zb >> 1;
  const unsigned short* in = (zb & 1 ? kb : qb) + (long)b * CNT;
  unsigned short* o = tr + (long)b * 2 * CNT + (zb & 1 ? CNT : 0);
  const int n0 = blockIdx.x * 64, c0 = blockIdx.y * 64;
  const int t = threadIdx.x;
  unsigned* ld32 = (unsigned*)ld;
  {
    const int p = t >> 3, cg = t & 7;
    uint4 r0 = *(const uint4*)(in + (long)(c0 + 2 * p) * 4096 + n0 + 8 * cg);
    uint4 r1 = *(const uint4*)(in + (long)(c0 + 2 * p + 1) * 4096 + n0 + 8 * cg);
    unsigned aw[4] = { r0.x, r0.y, r0.z, r0.w };
    unsigned bw[4] = { r1.x, r1.y, r1.z, r1.w };
    #pragma unroll
    for (int i = 0; i < 4; i++) {
      ld32[(8 * cg + 2 * i) * 36 + p]     = (aw[i] & 0xFFFFu) | (bw[i] << 16);
      ld32[(8 * cg + 2 * i + 1) * 36 + p] = (aw[i] >> 16) | (bw[i] & 0xFFFF0000u);
    }
  }
  __syncthreads();
  {
    const int n = t >> 2, cg2 = t & 3;
    uint4 o0 = *(const uint4*)(ld + n * 72 + 16 * cg2);
    uint4 o1 = *(const uint4*)(ld + n * 72 + 16 * cg2 + 8);
    *(uint4*)(o + (long)(n0 + n) * 512 + c0 + 16 * cg2)     = o0;
    *(uint4*)(o + (long)(n0 + n) * 512 + c0 + 16 * cg2 + 8) = o1;
  }
}

// ---------------- QK^T: 256x256 tiles, 8 waves, 4-deep static pipeline, grid (16,16,4) --------
__launch_bounds__(512, 1)
__global__ void qk_f16(const unsigned short* __restrict__ tr, unsigned short* __restrict__ attn) {
  __shared__ __align__(16) unsigned short LB[65536];   // 128 KB: 4 x 32 KB buffers
  const int b = blockIdx.z;
  const unsigned short* qT = tr + (long)b * 2 * CNT;
  const unsigned short* kT = qT + CNT;
  const int n0 = blockIdx.x * 256, m0 = blockIdx.y * 256;
  const int t = threadIdx.x;

  f32x4 acc[8][4];
  #pragma unroll
  for (int i = 0; i < 8; i++)
    #pragma unroll
    for (int j = 0; j < 4; j++) acc[i][j] = (f32x4){0.f, 0.f, 0.f, 0.f};

  gemm_core<256, 256, 2, 4, 8, 512, 4>(qT + (long)n0 * 512, 512, kT + (long)m0 * 512, 512, LB, t, acc);
  store_f16<256, 256, 2, 4, 8>(LB, acc, t, attn + (long)b * ACNT + (long)n0 * 4096 + m0, 4096,
                               nullptr);
}

// ---------------- Row softmax: fp16 in, fp16 out, in place (all batches) ----------------
__global__ void softmax_f16ip(unsigned short* __restrict__ attn) {
  unsigned short* p = attn + (long)blockIdx.x * HWDIM;
  const int t = threadIdx.x;                 // 16 shorts per thread
  uint4 u0 = *(const uint4*)(p + t * 16);
  uint4 u1 = *(const uint4*)(p + t * 16 + 8);
  float v[16];
  {
    unsigned uu[8] = { u0.x, u0.y, u0.z, u0.w, u1.x, u1.y, u1.z, u1.w };
    #pragma unroll
    for (int i = 0; i < 8; i++) { float2 f = up2(uu[i]); v[2*i] = f.x; v[2*i+1] = f.y; }
  }
  float mx = -1e30f;
  #pragma unroll
  for (int i = 0; i < 16; i++) mx = fmaxf(mx, v[i]);
  #pragma unroll
  for (int o = 32; o > 0; o >>= 1) mx = fmaxf(mx, __shfl_xor(mx, o, 64));
  __shared__ float rmax[4], rsum[4];
  if ((t & 63) == 0) rmax[t >> 6] = mx;
  __syncthreads();
  mx = fmaxf(fmaxf(rmax[0], rmax[1]), fmaxf(rmax[2], rmax[3]));
  float s = 0.f;
  #pragma unroll
  for (int i = 0; i < 16; i++) { v[i] = __expf(v[i] - mx); s += v[i]; }
  #pragma unroll
  for (int o = 32; o > 0; o >>= 1) s += __shfl_xor(s, o, 64);
  if ((t & 63) == 0) rsum[t >> 6] = s;
  __syncthreads();
  s = (rsum[0] + rsum[1]) + (rsum[2] + rsum[3]);
  float inv = 1.f / s;
  uint4 w0, w1;
  w0.x = pkf16(v[0]*inv,  v[1]*inv);  w0.y = pkf16(v[2]*inv,  v[3]*inv);
  w0.z = pkf16(v[4]*inv,  v[5]*inv);  w0.w = pkf16(v[6]*inv,  v[7]*inv);
  w1.x = pkf16(v[8]*inv,  v[9]*inv);  w1.y = pkf16(v[10]*inv, v[11]*inv);
  w1.z = pkf16(v[12]*inv, v[13]*inv); w1.w = pkf16(v[14]*inv, v[15]*inv);
  *(uint4*)(p + t * 16)     = w0;
  *(uint4*)(p + t * 16 + 8) = w1;
}

// ---------------- PV: 256x128 tiles, 8 waves (4Mx2N), unrolled 4-deep, grid (16,4,4) --------
__launch_bounds__(512, 1)
__global__ void pv_f16(const unsigned short* __restrict__ P, const unsigned short* __restrict__ V,
                       unsigned short* __restrict__ ot) {
  __shared__ __align__(16) unsigned short LB[49152];   // 96 KB: 4 x 24 KB
  const int b = blockIdx.z;
  const unsigned short* Pb = P + (long)b * ACNT;
  const unsigned short* Vb = V + (long)b * CNT;
  unsigned short* Ob = ot + (long)b * CNT;
  const int n0 = blockIdx.x * 256, c0 = blockIdx.y * 128;
  const int t = threadIdx.x;

  f32x4 acc[4][4];
  #pragma unroll
  for (int i = 0; i < 4; i++)
    #pragma unroll
    for (int j = 0; j < 4; j++) acc[i][j] = (f32x4){0.f, 0.f, 0.f, 0.f};

  gemm_core<256, 128, 4, 2, 4, 4096, 4>(Pb + (long)n0 * 4096, 4096, Vb + (long)c0 * 4096, 4096,
                                        LB, t, acc);
  store_f16<256, 128, 4, 2, 4>(LB, acc, t, Ob + (long)n0 * 512 + c0, 512, nullptr);
}

// ---------------- launch ----------------
extern "C" void kernel_launch(void* const* d_in, const int* in_sizes, int n_in,
                              void* d_out, int out_size, void* d_ws, size_t ws_size,
                              hipStream_t stream) {
  (void)in_sizes; (void)n_in; (void)out_size; (void)ws_size;
  const float* x  = (const float*)d_in[0];
  const float* gw = (const float*)d_in[1];
  const float* gb = (const float*)d_in[2];
  const float* wq = (const float*)d_in[3];
  const float* bq = (const float*)d_in[4];
  const float* wk = (const float*)d_in[5];
  const float* bk = (const float*)d_in[6];
  const float* wv = (const float*)d_in[7];
  const float* bv = (const float*)d_in[8];
  const float* wo = (const float*)d_in[9];
  const float* bo = (const float*)d_in[10];
  float* out = (float*)d_out;

  // Workspace (~226 MB of the 256 MiB, all fp16 except sacc):
  //  [attn 128MB | h 16MB aliases start][qf 16][kf 16][vf 16][tr 32][ot 16][wf 2][sacc]
  unsigned short* attn = (unsigned short*)d_ws;
  unsigned short* h    = attn;                 // dead before first qk write
  unsigned short* qf   = attn + 4 * ACNT;
  unsigned short* kf   = qf + 8388608;
  unsigned short* vf   = kf + 8388608;
  unsigned short* tr   = vf + 8388608;         // 4 batches x (qT|kT)
  unsigned short* ot   = tr + 16777216;
  unsigned short* wf   = ot + 8388608;
  float* sacc = (float*)(wf + 1048576);

  hipMemsetAsync(sacc, 0, 256 * sizeof(float), stream);
  gn_stats_kernel<<<dim3(512), dim3(256), 0, stream>>>(x, sacc);
  gn_norm_f16<<<dim3(8192), dim3(256), 0, stream>>>(x, sacc, gw, gb, h);
  wcvt<<<dim3(256, 4), dim3(256), 0, stream>>>(wq, wk, wv, wo, wf);

  proj_qkv<<<dim3(64, 4, 3), 256, 0, stream>>>(h, wf, bq, bk, bv, qf);

  transpose_f16<<<dim3(64, 8, 8), 256, 0, stream>>>(qf, kf, tr);
  qk_f16<<<dim3(16, 16, 4), 512, 0, stream>>>(tr, attn);
  softmax_f16ip<<<dim3(16384), 256, 0, stream>>>(attn);
  pv_f16<<<dim3(16, 4, 4), 512, 0, stream>>>(attn, vf, ot);

  proj_out<<<dim3(64, 4), 256, 0, stream>>>(ot, wf + 786432, bo, x, out);
}